// Round 20
// baseline (151.944 us; speedup 1.0000x reference)
//
#include <hip/hip_runtime.h>
#include <hip/hip_bf16.h>

#define M_TOTAL 65536
#define N_TOTAL 1024
#define K_TOTAL 1024

typedef __attribute__((ext_vector_type(8))) short short8;
typedef __attribute__((ext_vector_type(4))) float f32x4;
typedef __attribute__((ext_vector_type(4))) int   i32x4;

typedef __attribute__((address_space(3))) void lds_vp;
typedef const __attribute__((address_space(1))) void glb_vp;

#define BAR()    asm volatile("s_barrier" ::: "memory")
#define WAITV8() asm volatile("s_waitcnt vmcnt(8)" ::: "memory")
#define WAITV3() asm volatile("s_waitcnt vmcnt(3)" ::: "memory")
#define WAITV0() asm volatile("s_waitcnt vmcnt(0)" ::: "memory")
#define WAITL0() asm volatile("s_waitcnt lgkmcnt(0)" ::: "memory")

#define MAGIC 12582912.0f   // 1.5*2^23: low byte of (r+MAGIC) = (int8)rint(r)

static __device__ __forceinline__ unsigned fbits(float f) {
    union { float f; unsigned u; } c; c.f = f; return c.u;
}
// pack low bytes of 4 magic-biased floats into one dword (verified r6-r19)
static __device__ __forceinline__ unsigned pk4(float g0, float g1, float g2, float g3) {
    unsigned p01 = __builtin_amdgcn_perm(fbits(g1), fbits(g0), 0x0C0C0400u);
    unsigned p23 = __builtin_amdgcn_perm(fbits(g3), fbits(g2), 0x04000C0Cu);
    return p01 | p23;
}
// non-contracted multiply: keep rint semantics of (v*inv)+MAGIC exact
static __device__ __forceinline__ float mulnc(float a, float b) {
    float t = a * b; asm volatile("" : "+v"(t)); return t;
}
// pack hi16 halves (bf16 of integer-valued f32) — fallback path
static __device__ __forceinline__ unsigned pkhi(float lo, float hi) {
    return __builtin_amdgcn_perm(fbits(hi), fbits(lo), 0x07060302u);
}

// ===================== FAST PATH (i8) ========================================
// Xb/Wb: ROW-MAJOR i8 [row][1024], bank swizzle folded into each 64B group:
// physical 16B-slot s of row r holds logical slot s ^ ((r>>1)&3).
// (r10 layout; linear glds fill -> 0-conflict LDS image, proven r10-r19.)

// W: [1024][1024] f32 ints -> Wb row-major i8 (+ s_a tail). 1024 x 256.
__global__ void wconv8(const float* __restrict__ Wq, const float* __restrict__ SXp,
                       const float* __restrict__ SW, char* __restrict__ Wb,
                       float* __restrict__ Out) {
    const int n = blockIdx.x, t = threadIdx.x;
    float4 v = *(const float4*)(Wq + (size_t)n * K_TOTAL + t * 4);
    unsigned dw = pk4(v.x + MAGIC, v.y + MAGIC, v.z + MAGIC, v.w + MAGIC);
    const int p  = (n >> 1) & 3;
    const int db = t * 4;
    const int phys = (db & ~0x30) | ((((db >> 4) & 3) ^ p) << 4);
    *(unsigned*)(Wb + (size_t)n * 1024 + phys) = dw;
    if (t == 0)
        Out[(size_t)M_TOTAL * N_TOTAL + n] = SW[n] * SXp[0];
}

// X: [65536][1024] f32 -> Xb row-major i8. One wave per row (dense stream).
// NT loads: don't let the 268MB X stream evict Xb from L3 (Xb = 64MB, fits).
__global__ __launch_bounds__(256)
void xconv8(const float* __restrict__ X, const float* __restrict__ SXp,
            char* __restrict__ Xb) {
    const float inv_sx = 1.0f / SXp[0];
    const int lane = threadIdx.x & 63;
    const unsigned row = blockIdx.x * 4 + (threadIdx.x >> 6);   // 0..65535
    const float* src = X + (size_t)row * K_TOTAL;
    char* drow = Xb + (size_t)row * 1024;
    const int p = (row >> 1) & 3;
    #pragma unroll
    for (int q = 0; q < 4; ++q) {
        f32x4 v = __builtin_nontemporal_load(
            (const f32x4*)(src + q * 256 + lane * 4));
        unsigned dw = pk4(mulnc(v.x, inv_sx) + MAGIC, mulnc(v.y, inv_sx) + MAGIC,
                          mulnc(v.z, inv_sx) + MAGIC, mulnc(v.w, inv_sx) + MAGIC);
        const int db = q * 256 + lane * 4;
        const int phys = (db & ~0x30) | ((((db >> 4) & 3) ^ p) << 4);
        *(unsigned*)(drow + phys) = dw;
    }
}

// GEMM r20: r19 structure, single-variable A/B — CACHED epilogue stores
// (write-allocate through L2, full-line write-back) instead of NT.
__global__ __launch_bounds__(512, 4)
void qgemm8(const char* __restrict__ Xb, const float* __restrict__ SXp,
            const char* __restrict__ Wb, const float* __restrict__ SW,
            const float* __restrict__ Bq, float* __restrict__ Out)
{
    __shared__ uint4 smem4[4608];   // 72 KiB: A 3x8K @0, B 3x16K @24576
    char* const smem = (char*)smem4;

    const int tid = threadIdx.x;
    const int d = blockIdx.x;                    // 2048 blocks, 2048%8==0
    const int g = (d & 7) * 256 + (d >> 3);      // XCD-bijective
    const int bn_idx = g & 3, bm_idx = g >> 2;   // 4 bn-sharers same XCD

    const int lane = tid & 63, w = tid >> 6;     // 8 waves
    const int wm = (w >> 2) << 6;                // 0 / 64
    const int wn = (w & 3) << 6;                 // 0..192
    const int fr = lane & 15, fg = lane >> 4;
    const int sslot = ((fg ^ ((fr >> 1) & 3)) << 4);
    const int arow = (wm + fr) * 64;
    const int brow = (wn + fr) * 64;

    // glds sources (row-major, pre-swizzled). A: wave w fills LDS rows
    // w*16..w*16+15 (1 instr). B: rows w*32..w*32+31 (2 instrs).
    const char* asrc = Xb + ((size_t)bm_idx * 128 + w * 16 + (lane >> 2)) * 1024
                          + (lane & 3) * 16;
    const char* bsrc = Wb + ((size_t)bn_idx * 256 + w * 32 + (lane >> 2)) * 1024
                          + (lane & 3) * 16;

    const float sx = SXp[0], inv_sx = 1.0f / sx;

    i32x4 acc[4][4] = {};
    i32x4 af[4], bf0, bf1;

    auto glds = [&](int kt, int buf) {           // 3 instrs: A x1, B x2
        char* da = smem +         buf * 8192  + w * 1024;
        char* db = smem + 24576 + buf * 16384 + w * 2048;
        const char* sa = asrc + kt * 64;
        const char* sb = bsrc + kt * 64;
        __builtin_amdgcn_global_load_lds((glb_vp*)(sa +     0), (lds_vp*)(da +    0), 16, 0, 0);
        __builtin_amdgcn_global_load_lds((glb_vp*)(sb +     0), (lds_vp*)(db +    0), 16, 0, 0);
        __builtin_amdgcn_global_load_lds((glb_vp*)(sb + 16384), (lds_vp*)(db + 1024), 16, 0, 0);
    };

    // prologue: tiles 0 and 1 in flight (3 ops each per wave)
    glds(0, 0);
    glds(1, 1);

    #pragma unroll
    for (int t = 0; t < 16; ++t) {
        const int buf = t % 3;
        // retire exactly tile t's 3 glds; t+1's stay in flight
        if (t < 15) WAITV3(); else WAITV0();
        BAR();                               // all waves' glds(t) visible
        // WAR-safe: post-BAR all waves are past tile t-1 reads; (t+2)%3
        // differs from t%3 and (t+1)%3
        if (t + 2 < 16) glds(t + 2, (t + 2) % 3);

        const char* abp = smem +         buf * 8192  + arow + sslot;
        const char* bbp = smem + 24576 + buf * 16384 + brow + sslot;
        // ---- phase 0: A + B cols 0-1; 8 MFMA ----
        #pragma unroll
        for (int i = 0; i < 4; ++i)
            af[i] = *(const i32x4*)(abp + (i * 16) * 64);
        bf0 = *(const i32x4*)(bbp + 0 * 1024);
        bf1 = *(const i32x4*)(bbp + 1 * 1024);
        BAR();                               // phase alignment
        __builtin_amdgcn_s_setprio(1);
        #pragma unroll
        for (int i = 0; i < 4; ++i) {
            acc[i][0] = __builtin_amdgcn_mfma_i32_16x16x64_i8(af[i], bf0, acc[i][0], 0, 0, 0);
            acc[i][1] = __builtin_amdgcn_mfma_i32_16x16x64_i8(af[i], bf1, acc[i][1], 0, 0, 0);
        }
        __builtin_amdgcn_s_setprio(0);
        BAR();                               // phase boundary
        // ---- phase 1: B cols 2-3; 8 MFMA ----
        bf0 = *(const i32x4*)(bbp + 2 * 1024);
        bf1 = *(const i32x4*)(bbp + 3 * 1024);
        __builtin_amdgcn_s_setprio(1);
        #pragma unroll
        for (int i = 0; i < 4; ++i) {
            acc[i][2] = __builtin_amdgcn_mfma_i32_16x16x64_i8(af[i], bf0, acc[i][2], 0, 0, 0);
            acc[i][3] = __builtin_amdgcn_mfma_i32_16x16x64_i8(af[i], bf1, acc[i][3], 0, 0, 0);
        }
        __builtin_amdgcn_s_setprio(0);
    }

    // ---- epilogue: cross-wave LDS stage, full-1KiB-row CACHED stores -------
    // (acc_i32 + rint(b/s_x)) * (s_w*s_x); exact (|acc|+|b32| < 2^24).
    const int bm0 = bm_idx * 128, bn0 = bn_idx * 256;
    float saN[4], bN[4];
    #pragma unroll
    for (int n = 0; n < 4; ++n) {
        const int col = bn0 + wn + n * 16 + fr;
        saN[n] = SW[col] * sx;
        bN[n]  = rintf(Bq[col] * inv_sx);
    }
    float* const scr = (float*)smem;             // [32][260] f32 = 33280B
    const int roff = (w >> 2) * 16;              // wm group -> local rows
    BAR();   // all waves done with K-loop LDS before scr overwrites it
    #pragma unroll
    for (int m = 0; m < 4; ++m) {
        #pragma unroll
        for (int n = 0; n < 4; ++n)
            #pragma unroll
            for (int r = 0; r < 4; ++r)
                scr[(roff + fg * 4 + r) * 260 + wn + n * 16 + fr] =
                    ((float)acc[m][n][r] + bN[n]) * saN[n];
        BAR();                                   // chunk staged by all waves
        #pragma unroll
        for (int p = 0; p < 4; ++p) {
            const int lrow = w * 4 + p;          // 0..31
            f32x4 v = *(const f32x4*)&scr[lrow * 260 + lane * 4];
            const size_t orow = (size_t)(bm0 + ((lrow >= 16) ? 64 : 0)
                                         + m * 16 + (lrow & 15));
            *(f32x4*)&Out[orow * (size_t)N_TOTAL + bn0 + lane * 4] = v;
        }
        if (m < 3) BAR();                        // before next chunk reuse
    }
}

// ===================== FALLBACK (r5 bf16 kernel, 221us) ======================
__global__ void wconv_bf(const float* __restrict__ Wq, ushort* __restrict__ Wb) {
    const int n = blockIdx.x, c4 = threadIdx.x * 4;
    float4 v = *(const float4*)(Wq + (size_t)n * K_TOTAL + c4);
    const int bnb = n >> 8, row = n & 255, kt = c4 >> 6, c = c4 & 63;
    const int cs = c ^ ((row & 7) << 3);
    ushort* dst = Wb + ((size_t)(bnb * 16 + kt) * 16384 + row * 64 + cs);
    *(uint2*)dst = make_uint2(pkhi(v.x, v.y), pkhi(v.z, v.w));
}

__global__ __launch_bounds__(512, 2)
void qgemm_bf(const float* __restrict__ X, const float* __restrict__ SXp,
              const ushort* __restrict__ Wb, const float* __restrict__ SW,
              const float* __restrict__ Bq, float* __restrict__ Out)
{
    __shared__ uint4 smem4[8192];
    char* const smem = (char*)smem4;
    const int tid = threadIdx.x;
    const int d = blockIdx.x;
    const int g = (d & 7) * 128 + (d >> 3);
    const int bn_idx = g & 3, bm_idx = g >> 2;
    const int bm0 = bm_idx * 256, bn0 = bn_idx * 256;
    const float sx = SXp[0], inv_sx = 1.0f / sx;
    const int ar = tid >> 2, ac = (tid & 3) << 4;
    const float* xg = X + (size_t)(bm0 + ar) * K_TOTAL + ac;
    const int awslot = (tid & 3) << 1;
    const int awsw0 = ((awslot    ) ^ (ar & 7)) << 4;
    const int awsw1 = ((awslot + 1) ^ (ar & 7)) << 4;
    const int lane = tid & 63, w = tid >> 6;
    const int wm = (w >> 2) << 7, wn = (w & 3) << 6;
    const int fr = lane & 15, fg = lane >> 4;
    const int s0 = ((fg    ) ^ (fr & 7)) << 4;
    const int s1 = ((fg + 4) ^ (fr & 7)) << 4;
    const int arow = (wm + fr) * 128, brow = (wn + fr) * 128;
    const char* wsrc = (const char*)Wb + (size_t)bn_idx * 16 * 32768
                     + w * 4096 + lane * 16;
    f32x4 acc[8][4] = {};
    float4 xh0[4], xh1[4];
    short8 af[4], bf[4];
    auto issueA = [&](int kt, int h, float4* dst) {
        const float4* p = (const float4*)(xg + (size_t)h * 128 * K_TOTAL + kt * 64);
        dst[0] = p[0]; dst[1] = p[1]; dst[2] = p[2]; dst[3] = p[3];
    };
    auto packA = [&](int buf, int h, const float4* v) {
        unsigned u[8];
        #pragma unroll
        for (int q = 0; q < 4; ++q) {
            u[2*q+0] = pkhi(rintf(v[q].x * inv_sx), rintf(v[q].y * inv_sx));
            u[2*q+1] = pkhi(rintf(v[q].z * inv_sx), rintf(v[q].w * inv_sx));
        }
        char* base = smem + buf * 32768 + (h * 128 + ar) * 128;
        *(uint4*)(base + awsw0) = make_uint4(u[0], u[1], u[2], u[3]);
        *(uint4*)(base + awsw1) = make_uint4(u[4], u[5], u[6], u[7]);
    };
    auto gldsB = [&](int kt, int buf) {
        const char* src = wsrc + (size_t)kt * 32768;
        char* dst = smem + 65536 + buf * 32768 + w * 4096;
        __builtin_amdgcn_global_load_lds((glb_vp*)(src +    0), (lds_vp*)(dst +    0), 16, 0, 0);
        __builtin_amdgcn_global_load_lds((glb_vp*)(src + 1024), (lds_vp*)(dst + 1024), 16, 0, 0);
        __builtin_amdgcn_global_load_lds((glb_vp*)(src + 2048), (lds_vp*)(dst + 2048), 16, 0, 0);
        __builtin_amdgcn_global_load_lds((glb_vp*)(src + 3072), (lds_vp*)(dst + 3072), 16, 0, 0);
    };
    auto readA = [&](int buf, int mh, int sk) {
        const char* base = smem + buf * 32768 + arow;
        #pragma unroll
        for (int i = 0; i < 4; ++i)
            af[i] = *(const short8*)(base + (mh * 64 + i * 16) * 128 + sk);
    };
    auto readB = [&](int buf, int sk) {
        const char* base = smem + 65536 + buf * 32768 + brow;
        #pragma unroll
        for (int j = 0; j < 4; ++j)
            bf[j] = *(const short8*)(base + (j * 16) * 128 + sk);
    };
    auto mfma16 = [&](int mh) {
        __builtin_amdgcn_s_setprio(1);
        #pragma unroll
        for (int i = 0; i < 4; ++i)
            #pragma unroll
            for (int j = 0; j < 4; ++j)
                acc[mh*4+i][j] = __builtin_amdgcn_mfma_f32_16x16x32_bf16(
                    af[i], bf[j], acc[mh*4+i][j], 0, 0, 0);
        __builtin_amdgcn_s_setprio(0);
    };
    issueA(0, 0, xh0); issueA(0, 1, xh1);
    gldsB(0, 0);
    packA(0, 0, xh0); packA(0, 1, xh1);
    issueA(1, 0, xh0); issueA(1, 1, xh1);
    WAITV8(); WAITL0(); BAR();
    for (int t = 0; t < 16; ++t) {
        const int cur = t & 1, nxt = cur ^ 1;
        const bool pf  = (t + 1 < 16);
        const bool pf2 = (t + 2 < 16);
        if (pf) gldsB(t + 1, nxt);
        readA(cur, 0, s0); readB(cur, s0);
        BAR(); mfma16(0); BAR();
        readA(cur, 1, s0);
        BAR(); mfma16(1); BAR();
        if (pf)  packA(nxt, 0, xh0);
        if (pf2) issueA(t + 2, 0, xh0);
        readA(cur, 0, s1); readB(cur, s1);
        BAR(); mfma16(0); BAR();
        if (pf)  packA(nxt, 1, xh1);
        if (pf2) issueA(t + 2, 1, xh1);
        readA(cur, 1, s1);
        BAR(); mfma16(1);
        if (pf) {
            if (pf2) WAITV8(); else WAITV0();
            WAITL0(); BAR();
        }
    }
    #pragma unroll
    for (int n = 0; n < 4; ++n) {
        const int col = bn0 + wn + n * 16 + fr;
        const float sa  = SW[col] * sx;
        const float b32 = rintf(Bq[col] * inv_sx);
        #pragma unroll
        for (int m = 0; m < 8; ++m) {
            const size_t r0 = (size_t)(bm0 + wm + m * 16 + fg * 4) * N_TOTAL + col;
            #pragma unroll
            for (int r = 0; r < 4; ++r)
                Out[r0 + (size_t)r * N_TOTAL] = (acc[m][n][r] + b32) * sa;
        }
    }
}

__global__ void sa_tail(const float* __restrict__ SW, const float* __restrict__ SXp,
                        float* __restrict__ Out)
{
    int o = blockIdx.x * blockDim.x + threadIdx.x;
    if (o < N_TOTAL) Out[(size_t)M_TOTAL * N_TOTAL + o] = SW[o] * SXp[0];
}

extern "C" void kernel_launch(void* const* d_in, const int* in_sizes, int n_in,
                              void* d_out, int out_size, void* d_ws, size_t ws_size,
                              hipStream_t stream)
{
    const float* x  = (const float*)d_in[0];
    const float* sx = (const float*)d_in[1];
    const float* wq = (const float*)d_in[2];
    const float* sw = (const float*)d_in[3];
    const float* bq = (const float*)d_in[4];
    float* out = (float*)d_out;

    const size_t W_BYTES = 1u << 20;          // Wb: 1 MiB
    const size_t X_BYTES = (size_t)64 << 20;  // Xb: 64 MiB

    if (ws_size >= W_BYTES + X_BYTES) {
        char* wbuf = (char*)d_ws;
        char* xbuf = (char*)d_ws + W_BYTES;
        wconv8<<<1024, 256, 0, stream>>>(wq, sx, sw, wbuf, out);
        xconv8<<<16384, 256, 0, stream>>>(x, sx, xbuf);
        qgemm8<<<2048, 512, 0, stream>>>(xbuf, sx, wbuf, sw, bq, out);
    } else {
        ushort* wbuf = (ushort*)d_ws;         // 2 MiB (r5 path)
        wconv_bf<<<1024, 256, 0, stream>>>(wq, wbuf);
        qgemm_bf<<<1024, 512, 0, stream>>>(x, sx, wbuf, sw, bq, out);
        sa_tail<<<4, 256, 0, stream>>>(sw, sx, out);
    }
}

// Round 21
// 141.460 us; speedup vs baseline: 1.0741x; 1.0741x over previous
//
#include <hip/hip_runtime.h>
#include <hip/hip_bf16.h>

#define M_TOTAL 65536
#define N_TOTAL 1024
#define K_TOTAL 1024

typedef __attribute__((ext_vector_type(8))) short short8;
typedef __attribute__((ext_vector_type(4))) float f32x4;
typedef __attribute__((ext_vector_type(4))) int   i32x4;

typedef __attribute__((address_space(3))) void lds_vp;
typedef const __attribute__((address_space(1))) void glb_vp;

#define BAR()    asm volatile("s_barrier" ::: "memory")
#define WAITV8() asm volatile("s_waitcnt vmcnt(8)" ::: "memory")
#define WAITV3() asm volatile("s_waitcnt vmcnt(3)" ::: "memory")
#define WAITV0() asm volatile("s_waitcnt vmcnt(0)" ::: "memory")
#define WAITL0() asm volatile("s_waitcnt lgkmcnt(0)" ::: "memory")

#define MAGIC 12582912.0f   // 1.5*2^23: low byte of (r+MAGIC) = (int8)rint(r)

static __device__ __forceinline__ unsigned fbits(float f) {
    union { float f; unsigned u; } c; c.f = f; return c.u;
}
// pack low bytes of 4 magic-biased floats into one dword (verified r6-r20)
static __device__ __forceinline__ unsigned pk4(float g0, float g1, float g2, float g3) {
    unsigned p01 = __builtin_amdgcn_perm(fbits(g1), fbits(g0), 0x0C0C0400u);
    unsigned p23 = __builtin_amdgcn_perm(fbits(g3), fbits(g2), 0x04000C0Cu);
    return p01 | p23;
}
// non-contracted multiply: keep rint semantics of (v*inv)+MAGIC exact
static __device__ __forceinline__ float mulnc(float a, float b) {
    float t = a * b; asm volatile("" : "+v"(t)); return t;
}
// pack hi16 halves (bf16 of integer-valued f32) — fallback path
static __device__ __forceinline__ unsigned pkhi(float lo, float hi) {
    return __builtin_amdgcn_perm(fbits(hi), fbits(lo), 0x07060302u);
}

// ===================== FAST PATH (i8) ========================================
// Xb/Wb: ROW-MAJOR i8 [row][1024], bank swizzle folded into each 64B group:
// physical 16B-slot s of row r holds logical slot s ^ ((r>>1)&3).
// (r10 layout; linear glds fill -> 0-conflict LDS image, proven r10-r19.)

// MERGED prepass (r21): blocks 0..1023 convert W (+ s_a tail); blocks
// 1024..17407 quantize X. Removes the wconv->xconv kernel-boundary
// serialization and one graph launch.
__global__ __launch_bounds__(256)
void prep8(const float* __restrict__ Wq, const float* __restrict__ X,
           const float* __restrict__ SXp, const float* __restrict__ SW,
           char* __restrict__ Wb, char* __restrict__ Xb,
           float* __restrict__ Out)
{
    const int tid = threadIdx.x;
    if (blockIdx.x < 1024) {
        // ---- W convert: row-major i8, pre-swizzled ----
        const int n = blockIdx.x;
        float4 v = *(const float4*)(Wq + (size_t)n * K_TOTAL + tid * 4);
        unsigned dw = pk4(v.x + MAGIC, v.y + MAGIC, v.z + MAGIC, v.w + MAGIC);
        const int p  = (n >> 1) & 3;
        const int db = tid * 4;
        const int phys = (db & ~0x30) | ((((db >> 4) & 3) ^ p) << 4);
        *(unsigned*)(Wb + (size_t)n * 1024 + phys) = dw;
        if (tid == 0)
            Out[(size_t)M_TOTAL * N_TOTAL + n] = SW[n] * SXp[0];
    } else {
        // ---- X quantize: one wave per row, dense stream, NT reads ----
        const float inv_sx = 1.0f / SXp[0];
        const int lane = tid & 63;
        const unsigned row = (blockIdx.x - 1024) * 4 + (tid >> 6);  // 0..65535
        const float* src = X + (size_t)row * K_TOTAL;
        char* drow = Xb + (size_t)row * 1024;
        const int p = (row >> 1) & 3;
        #pragma unroll
        for (int q = 0; q < 4; ++q) {
            f32x4 v = __builtin_nontemporal_load(
                (const f32x4*)(src + q * 256 + lane * 4));
            unsigned dw = pk4(mulnc(v.x, inv_sx) + MAGIC, mulnc(v.y, inv_sx) + MAGIC,
                              mulnc(v.z, inv_sx) + MAGIC, mulnc(v.w, inv_sx) + MAGIC);
            const int db = q * 256 + lane * 4;
            const int phys = (db & ~0x30) | ((((db >> 4) & 3) ^ p) << 4);
            *(unsigned*)(drow + phys) = dw;
        }
    }
}

// GEMM r21 == r19 champion: 128x256 tile, 8 waves 2Mx4N, BK=64, 3-buffer LDS,
// counted WAITV3, 2-phase MFMA, 16 waves/CU, cross-wave LDS-staged epilogue
// with full-1KiB-row NT stores.
__global__ __launch_bounds__(512, 4)
void qgemm8(const char* __restrict__ Xb, const float* __restrict__ SXp,
            const char* __restrict__ Wb, const float* __restrict__ SW,
            const float* __restrict__ Bq, float* __restrict__ Out)
{
    __shared__ uint4 smem4[4608];   // 72 KiB: A 3x8K @0, B 3x16K @24576
    char* const smem = (char*)smem4;

    const int tid = threadIdx.x;
    const int d = blockIdx.x;                    // 2048 blocks, 2048%8==0
    const int g = (d & 7) * 256 + (d >> 3);      // XCD-bijective
    const int bn_idx = g & 3, bm_idx = g >> 2;   // 4 bn-sharers same XCD

    const int lane = tid & 63, w = tid >> 6;     // 8 waves
    const int wm = (w >> 2) << 6;                // 0 / 64
    const int wn = (w & 3) << 6;                 // 0..192
    const int fr = lane & 15, fg = lane >> 4;
    const int sslot = ((fg ^ ((fr >> 1) & 3)) << 4);
    const int arow = (wm + fr) * 64;
    const int brow = (wn + fr) * 64;

    // glds sources (row-major, pre-swizzled). A: wave w fills LDS rows
    // w*16..w*16+15 (1 instr). B: rows w*32..w*32+31 (2 instrs).
    const char* asrc = Xb + ((size_t)bm_idx * 128 + w * 16 + (lane >> 2)) * 1024
                          + (lane & 3) * 16;
    const char* bsrc = Wb + ((size_t)bn_idx * 256 + w * 32 + (lane >> 2)) * 1024
                          + (lane & 3) * 16;

    const float sx = SXp[0], inv_sx = 1.0f / sx;

    i32x4 acc[4][4] = {};
    i32x4 af[4], bf0, bf1;

    auto glds = [&](int kt, int buf) {           // 3 instrs: A x1, B x2
        char* da = smem +         buf * 8192  + w * 1024;
        char* db = smem + 24576 + buf * 16384 + w * 2048;
        const char* sa = asrc + kt * 64;
        const char* sb = bsrc + kt * 64;
        __builtin_amdgcn_global_load_lds((glb_vp*)(sa +     0), (lds_vp*)(da +    0), 16, 0, 0);
        __builtin_amdgcn_global_load_lds((glb_vp*)(sb +     0), (lds_vp*)(db +    0), 16, 0, 0);
        __builtin_amdgcn_global_load_lds((glb_vp*)(sb + 16384), (lds_vp*)(db + 1024), 16, 0, 0);
    };

    // prologue: tiles 0 and 1 in flight (3 ops each per wave)
    glds(0, 0);
    glds(1, 1);

    #pragma unroll
    for (int t = 0; t < 16; ++t) {
        const int buf = t % 3;
        // retire exactly tile t's 3 glds; t+1's stay in flight
        if (t < 15) WAITV3(); else WAITV0();
        BAR();                               // all waves' glds(t) visible
        // WAR-safe: post-BAR all waves are past tile t-1 reads; (t+2)%3
        // differs from t%3 and (t+1)%3
        if (t + 2 < 16) glds(t + 2, (t + 2) % 3);

        const char* abp = smem +         buf * 8192  + arow + sslot;
        const char* bbp = smem + 24576 + buf * 16384 + brow + sslot;
        // ---- phase 0: A + B cols 0-1; 8 MFMA ----
        #pragma unroll
        for (int i = 0; i < 4; ++i)
            af[i] = *(const i32x4*)(abp + (i * 16) * 64);
        bf0 = *(const i32x4*)(bbp + 0 * 1024);
        bf1 = *(const i32x4*)(bbp + 1 * 1024);
        BAR();                               // phase alignment
        __builtin_amdgcn_s_setprio(1);
        #pragma unroll
        for (int i = 0; i < 4; ++i) {
            acc[i][0] = __builtin_amdgcn_mfma_i32_16x16x64_i8(af[i], bf0, acc[i][0], 0, 0, 0);
            acc[i][1] = __builtin_amdgcn_mfma_i32_16x16x64_i8(af[i], bf1, acc[i][1], 0, 0, 0);
        }
        __builtin_amdgcn_s_setprio(0);
        BAR();                               // phase boundary
        // ---- phase 1: B cols 2-3; 8 MFMA ----
        bf0 = *(const i32x4*)(bbp + 2 * 1024);
        bf1 = *(const i32x4*)(bbp + 3 * 1024);
        __builtin_amdgcn_s_setprio(1);
        #pragma unroll
        for (int i = 0; i < 4; ++i) {
            acc[i][2] = __builtin_amdgcn_mfma_i32_16x16x64_i8(af[i], bf0, acc[i][2], 0, 0, 0);
            acc[i][3] = __builtin_amdgcn_mfma_i32_16x16x64_i8(af[i], bf1, acc[i][3], 0, 0, 0);
        }
        __builtin_amdgcn_s_setprio(0);
    }

    // ---- epilogue: cross-wave LDS stage, full-1KiB-row NT stores -----------
    // (acc_i32 + rint(b/s_x)) * (s_w*s_x); exact (|acc|+|b32| < 2^24).
    const int bm0 = bm_idx * 128, bn0 = bn_idx * 256;
    float saN[4], bN[4];
    #pragma unroll
    for (int n = 0; n < 4; ++n) {
        const int col = bn0 + wn + n * 16 + fr;
        saN[n] = SW[col] * sx;
        bN[n]  = rintf(Bq[col] * inv_sx);
    }
    float* const scr = (float*)smem;             // [32][260] f32 = 33280B
    const int roff = (w >> 2) * 16;              // wm group -> local rows
    BAR();   // all waves done with K-loop LDS before scr overwrites it
    #pragma unroll
    for (int m = 0; m < 4; ++m) {
        #pragma unroll
        for (int n = 0; n < 4; ++n)
            #pragma unroll
            for (int r = 0; r < 4; ++r)
                scr[(roff + fg * 4 + r) * 260 + wn + n * 16 + fr] =
                    ((float)acc[m][n][r] + bN[n]) * saN[n];
        BAR();                                   // chunk staged by all waves
        #pragma unroll
        for (int p = 0; p < 4; ++p) {
            const int lrow = w * 4 + p;          // 0..31
            f32x4 v = *(const f32x4*)&scr[lrow * 260 + lane * 4];
            const size_t orow = (size_t)(bm0 + ((lrow >= 16) ? 64 : 0)
                                         + m * 16 + (lrow & 15));
            __builtin_nontemporal_store(v,
                (f32x4*)&Out[orow * (size_t)N_TOTAL + bn0 + lane * 4]);
        }
        if (m < 3) BAR();                        // before next chunk reuse
    }
}

// ===================== FALLBACK (r5 bf16 kernel, 221us) ======================
__global__ void wconv_bf(const float* __restrict__ Wq, ushort* __restrict__ Wb) {
    const int n = blockIdx.x, c4 = threadIdx.x * 4;
    float4 v = *(const float4*)(Wq + (size_t)n * K_TOTAL + c4);
    const int bnb = n >> 8, row = n & 255, kt = c4 >> 6, c = c4 & 63;
    const int cs = c ^ ((row & 7) << 3);
    ushort* dst = Wb + ((size_t)(bnb * 16 + kt) * 16384 + row * 64 + cs);
    *(uint2*)dst = make_uint2(pkhi(v.x, v.y), pkhi(v.z, v.w));
}

__global__ __launch_bounds__(512, 2)
void qgemm_bf(const float* __restrict__ X, const float* __restrict__ SXp,
              const ushort* __restrict__ Wb, const float* __restrict__ SW,
              const float* __restrict__ Bq, float* __restrict__ Out)
{
    __shared__ uint4 smem4[8192];
    char* const smem = (char*)smem4;
    const int tid = threadIdx.x;
    const int d = blockIdx.x;
    const int g = (d & 7) * 128 + (d >> 3);
    const int bn_idx = g & 3, bm_idx = g >> 2;
    const int bm0 = bm_idx * 256, bn0 = bn_idx * 256;
    const float sx = SXp[0], inv_sx = 1.0f / sx;
    const int ar = tid >> 2, ac = (tid & 3) << 4;
    const float* xg = X + (size_t)(bm0 + ar) * K_TOTAL + ac;
    const int awslot = (tid & 3) << 1;
    const int awsw0 = ((awslot    ) ^ (ar & 7)) << 4;
    const int awsw1 = ((awslot + 1) ^ (ar & 7)) << 4;
    const int lane = tid & 63, w = tid >> 6;
    const int wm = (w >> 2) << 7, wn = (w & 3) << 6;
    const int fr = lane & 15, fg = lane >> 4;
    const int s0 = ((fg    ) ^ (fr & 7)) << 4;
    const int s1 = ((fg + 4) ^ (fr & 7)) << 4;
    const int arow = (wm + fr) * 128, brow = (wn + fr) * 128;
    const char* wsrc = (const char*)Wb + (size_t)bn_idx * 16 * 32768
                     + w * 4096 + lane * 16;
    f32x4 acc[8][4] = {};
    float4 xh0[4], xh1[4];
    short8 af[4], bf[4];
    auto issueA = [&](int kt, int h, float4* dst) {
        const float4* p = (const float4*)(xg + (size_t)h * 128 * K_TOTAL + kt * 64);
        dst[0] = p[0]; dst[1] = p[1]; dst[2] = p[2]; dst[3] = p[3];
    };
    auto packA = [&](int buf, int h, const float4* v) {
        unsigned u[8];
        #pragma unroll
        for (int q = 0; q < 4; ++q) {
            u[2*q+0] = pkhi(rintf(v[q].x * inv_sx), rintf(v[q].y * inv_sx));
            u[2*q+1] = pkhi(rintf(v[q].z * inv_sx), rintf(v[q].w * inv_sx));
        }
        char* base = smem + buf * 32768 + (h * 128 + ar) * 128;
        *(uint4*)(base + awsw0) = make_uint4(u[0], u[1], u[2], u[3]);
        *(uint4*)(base + awsw1) = make_uint4(u[4], u[5], u[6], u[7]);
    };
    auto gldsB = [&](int kt, int buf) {
        const char* src = wsrc + (size_t)kt * 32768;
        char* dst = smem + 65536 + buf * 32768 + w * 4096;
        __builtin_amdgcn_global_load_lds((glb_vp*)(src +    0), (lds_vp*)(dst +    0), 16, 0, 0);
        __builtin_amdgcn_global_load_lds((glb_vp*)(src + 1024), (lds_vp*)(dst + 1024), 16, 0, 0);
        __builtin_amdgcn_global_load_lds((glb_vp*)(src + 2048), (lds_vp*)(dst + 2048), 16, 0, 0);
        __builtin_amdgcn_global_load_lds((glb_vp*)(src + 3072), (lds_vp*)(dst + 3072), 16, 0, 0);
    };
    auto readA = [&](int buf, int mh, int sk) {
        const char* base = smem + buf * 32768 + arow;
        #pragma unroll
        for (int i = 0; i < 4; ++i)
            af[i] = *(const short8*)(base + (mh * 64 + i * 16) * 128 + sk);
    };
    auto readB = [&](int buf, int sk) {
        const char* base = smem + 65536 + buf * 32768 + brow;
        #pragma unroll
        for (int j = 0; j < 4; ++j)
            bf[j] = *(const short8*)(base + (j * 16) * 128 + sk);
    };
    auto mfma16 = [&](int mh) {
        __builtin_amdgcn_s_setprio(1);
        #pragma unroll
        for (int i = 0; i < 4; ++i)
            #pragma unroll
            for (int j = 0; j < 4; ++j)
                acc[mh*4+i][j] = __builtin_amdgcn_mfma_f32_16x16x32_bf16(
                    af[i], bf[j], acc[mh*4+i][j], 0, 0, 0);
        __builtin_amdgcn_s_setprio(0);
    };
    issueA(0, 0, xh0); issueA(0, 1, xh1);
    gldsB(0, 0);
    packA(0, 0, xh0); packA(0, 1, xh1);
    issueA(1, 0, xh0); issueA(1, 1, xh1);
    WAITV8(); WAITL0(); BAR();
    for (int t = 0; t < 16; ++t) {
        const int cur = t & 1, nxt = cur ^ 1;
        const bool pf  = (t + 1 < 16);
        const bool pf2 = (t + 2 < 16);
        if (pf) gldsB(t + 1, nxt);
        readA(cur, 0, s0); readB(cur, s0);
        BAR(); mfma16(0); BAR();
        readA(cur, 1, s0);
        BAR(); mfma16(1); BAR();
        if (pf)  packA(nxt, 0, xh0);
        if (pf2) issueA(t + 2, 0, xh0);
        readA(cur, 0, s1); readB(cur, s1);
        BAR(); mfma16(0); BAR();
        if (pf)  packA(nxt, 1, xh1);
        if (pf2) issueA(t + 2, 1, xh1);
        readA(cur, 1, s1);
        BAR(); mfma16(1);
        if (pf) {
            if (pf2) WAITV8(); else WAITV0();
            WAITL0(); BAR();
        }
    }
    #pragma unroll
    for (int n = 0; n < 4; ++n) {
        const int col = bn0 + wn + n * 16 + fr;
        const float sa  = SW[col] * sx;
        const float b32 = rintf(Bq[col] * inv_sx);
        #pragma unroll
        for (int m = 0; m < 8; ++m) {
            const size_t r0 = (size_t)(bm0 + wm + m * 16 + fg * 4) * N_TOTAL + col;
            #pragma unroll
            for (int r = 0; r < 4; ++r)
                Out[r0 + (size_t)r * N_TOTAL] = (acc[m][n][r] + b32) * sa;
        }
    }
}

__global__ void sa_tail(const float* __restrict__ SW, const float* __restrict__ SXp,
                        float* __restrict__ Out)
{
    int o = blockIdx.x * blockDim.x + threadIdx.x;
    if (o < N_TOTAL) Out[(size_t)M_TOTAL * N_TOTAL + o] = SW[o] * SXp[0];
}

extern "C" void kernel_launch(void* const* d_in, const int* in_sizes, int n_in,
                              void* d_out, int out_size, void* d_ws, size_t ws_size,
                              hipStream_t stream)
{
    const float* x  = (const float*)d_in[0];
    const float* sx = (const float*)d_in[1];
    const float* wq = (const float*)d_in[2];
    const float* sw = (const float*)d_in[3];
    const float* bq = (const float*)d_in[4];
    float* out = (float*)d_out;

    const size_t W_BYTES = 1u << 20;          // Wb: 1 MiB
    const size_t X_BYTES = (size_t)64 << 20;  // Xb: 64 MiB

    if (ws_size >= W_BYTES + X_BYTES) {
        char* wbuf = (char*)d_ws;
        char* xbuf = (char*)d_ws + W_BYTES;
        prep8<<<1024 + 16384, 256, 0, stream>>>(wq, x, sx, sw, wbuf, xbuf, out);
        qgemm8<<<2048, 512, 0, stream>>>(xbuf, sx, wbuf, sw, bq, out);
    } else {
        ushort* wbuf = (ushort*)d_ws;         // 2 MiB (r5 path)
        wconv_bf<<<1024, 256, 0, stream>>>(wq, wbuf);
        qgemm_bf<<<1024, 512, 0, stream>>>(x, sx, wbuf, sw, bq, out);
        sa_tail<<<4, 256, 0, stream>>>(sw, sx, out);
    }
}